// Round 6
// baseline (316.023 us; speedup 1.0000x reference)
//
#include <hip/hip_runtime.h>

#define BATCH 1024
#define NCOLS 8192
#define NROWS 8192
#define NNZPR 32
#define BT3   128   // batches per block
#define RB3   32    // rows per block (128B-contiguous output stores)

// round-to-nearest-even f32 -> bf16
__device__ __forceinline__ uint f2bf(float f) {
    uint u = __float_as_uint(f);
    return (u + 0x7fffu + ((u >> 16) & 1u)) >> 16;
}

// ---------------------------------------------------------------------------
// Kernel 1: transpose+convert X (BATCH x NCOLS f32) -> XTH (NCOLS x BATCH bf16)
// ---------------------------------------------------------------------------
__global__ __launch_bounds__(256) void transpose_bf16(const float* __restrict__ x,
                                                      uint* __restrict__ xth) {
    __shared__ float tile[64][65];
    const int c0 = blockIdx.x * 64;
    const int b0 = blockIdx.y * 64;
    const int t  = threadIdx.x;
    const int tx = t & 63;
    const int ty = t >> 6;

#pragma unroll
    for (int i = 0; i < 16; ++i) {
        const int b = ty + i * 4;
        tile[b][tx] = x[(size_t)(b0 + b) * NCOLS + c0 + tx];
    }
    __syncthreads();

    const int tx2 = t & 31;      // packed-uint column (2 batches)
    const int h   = t >> 5;      // 0..7
#pragma unroll
    for (int i = 0; i < 8; ++i) {
        const int c = h + i * 8;
        const uint lo = f2bf(tile[2 * tx2 + 0][c]);   // 2-way LDS alias: free
        const uint hi = f2bf(tile[2 * tx2 + 1][c]);
        xth[(size_t)(c0 + c) * (BATCH / 2) + (b0 >> 1) + tx2] = lo | (hi << 16);
    }
}

// ---------------------------------------------------------------------------
// Kernel 2 (main): 32-row x 128-batch tiles on bf16 XTH.
//   Memory side proven optimal in r5 (FETCH 16.5MB, WRITE 32MB). r5's failure
//   was VGPR=220 -> 1 block/CU. Controls:
//     - __launch_bounds__(256,4): cap 128 VGPR -> 4 blocks/CU = 16 waves/CU
//     - sched_barrier(0) between passes: stop cross-pass load hoisting;
//       depth-2 pipeline lives WITHIN a pass (8 loads in flight/wave)
// ---------------------------------------------------------------------------
#define FMAQ(L, V) do {                                      \
    const float v_ = __int_as_float(V);                      \
    ax += __uint_as_float((L).x << 16) * v_;                 \
    ay += __uint_as_float((L).x & 0xffff0000u) * v_;         \
    az += __uint_as_float((L).y << 16) * v_;                 \
    aw += __uint_as_float((L).y & 0xffff0000u) * v_;         \
} while (0)

__global__ __launch_bounds__(256, 4) void spmm_v6(const ushort* __restrict__ xth,
                                                  const float* __restrict__ vals,
                                                  const int*   __restrict__ cols,
                                                  float* __restrict__ out) {
    // phase 1: 1024 int2 pairs (8 KiB); phase 2: float[32][130] (16640 B)
    __shared__ __align__(16) char smem[RB3 * 130 * 4];
    int2* s_pair = (int2*)smem;

    const int bid = blockIdx.x;
    const int bt  = bid & 7;         // batch tile -> XCD id
    const int rt  = bid >> 3;        // row tile 0..255
    const int t   = threadIdx.x;

    const int nnzbase = rt * RB3 * NNZPR;
    for (int i = t; i < RB3 * NNZPR; i += 256) {
        int2 p;
        p.x = cols[nnzbase + i] << 11;          // byte offset: col*BATCH*2
        p.y = __float_as_int(vals[nnzbase + i]);
        s_pair[i] = p;
    }
    __syncthreads();

    const int hw = t >> 5;           // half-wave id 0..7 (row within pass)
    const int sl = t & 31;           // batch-quad within row
    const char* __restrict__ xb = (const char*)xth + (bt * BT3 + sl * 4) * 2;

    float4 accs[4];                  // static indexing (pass loop unrolled)

#pragma unroll
    for (int pass = 0; pass < 4; ++pass) {
        const int row = pass * 8 + hw;
        const int4* mrow = (const int4*)(s_pair + row * NNZPR);  // 16 int4

        int4 ma = mrow[0], mb = mrow[1];
        uint2 l0 = *(const uint2*)(xb + ma.x);
        uint2 l1 = *(const uint2*)(xb + ma.z);
        uint2 l2 = *(const uint2*)(xb + mb.x);
        uint2 l3 = *(const uint2*)(xb + mb.z);

        float ax = 0.f, ay = 0.f, az = 0.f, aw = 0.f;
#pragma unroll
        for (int g = 0; g < 7; ++g) {
            // prefetch group g+1 (independent of current FMAs)
            int4 na = mrow[2 * g + 2], nb = mrow[2 * g + 3];
            uint2 n0 = *(const uint2*)(xb + na.x);
            uint2 n1 = *(const uint2*)(xb + na.z);
            uint2 n2 = *(const uint2*)(xb + nb.x);
            uint2 n3 = *(const uint2*)(xb + nb.z);
            // consume group g
            FMAQ(l0, ma.y); FMAQ(l1, ma.w);
            FMAQ(l2, mb.y); FMAQ(l3, mb.w);
            ma = na; mb = nb; l0 = n0; l1 = n1; l2 = n2; l3 = n3;
        }
        FMAQ(l0, ma.y); FMAQ(l1, ma.w);
        FMAQ(l2, mb.y); FMAQ(l3, mb.w);
        accs[pass].x = ax; accs[pass].y = ay;
        accs[pass].z = az; accs[pass].w = aw;

        // fence: keep each pass's loads inside the pass (r5: VGPR 220 -> occ 10%)
        __builtin_amdgcn_sched_barrier(0);
    }
    __syncthreads();   // all s_pair reads done; reuse LDS as output tile

    float* tile = (float*)smem;      // [32][130]; 130%32==2 -> 2-way readout
#pragma unroll
    for (int pass = 0; pass < 4; ++pass) {
        const int row = pass * 8 + hw;
        float* dst = tile + row * 130 + sl * 4;   // 8B-aligned
        *(float2*)(dst + 0) = make_float2(accs[pass].x, accs[pass].y);
        *(float2*)(dst + 2) = make_float2(accs[pass].z, accs[pass].w);
    }
    __syncthreads();

    const int rr = t & 31;           // row within tile
    const int bq = t >> 5;           // 0..7
    const size_t obase = (size_t)(bt * BT3) * NROWS + (size_t)(rt * RB3);
#pragma unroll
    for (int p = 0; p < 16; ++p) {
        const int b = p * 8 + bq;    // batch within tile
        out[obase + (size_t)b * NROWS + rr] = tile[rr * 130 + b];
    }
}

// ---------------------------------------------------------------------------
// Fallback (ws too small for XTH): scalar gather straight from X.
// ---------------------------------------------------------------------------
__global__ __launch_bounds__(256) void spmm_fallback(const float* __restrict__ x,
                                                     const float* __restrict__ vals,
                                                     const int*   __restrict__ cols,
                                                     float* __restrict__ out) {
    __shared__ __align__(16) char smem[64 * 65 * 4];
    int*   s_col = (int*)smem;
    float* s_val = (float*)(smem + 64 * 32 * 4);

    const int bid  = blockIdx.x;
    const int bt   = bid & 15;
    const int rt   = bid >> 4;
    const int t    = threadIdx.x;
    const int lane = t & 63;
    const int wave = t >> 6;

    const int nnzbase = rt * 64 * NNZPR;
    for (int i = t; i < 64 * NNZPR; i += 256) {
        s_col[i] = cols[nnzbase + i];
        s_val[i] = vals[nnzbase + i];
    }
    __syncthreads();

    const int b = bt * 64 + lane;
    const float* __restrict__ xb = x + (size_t)b * NCOLS;

    const int rbase = wave * 16;
    float acc[16];
#pragma unroll
    for (int i = 0; i < 16; ++i) acc[i] = 0.f;

    for (int i = 0; i < 16; ++i) {
        const int p = (rbase + i) * NNZPR;
        float a = 0.f;
#pragma unroll
        for (int k = 0; k < NNZPR; ++k)
            a += xb[s_col[p + k]] * s_val[p + k];
        acc[i] = a;
    }
    __syncthreads();

    float* tile = (float*)smem;
#pragma unroll
    for (int i = 0; i < 16; ++i)
        tile[lane * 65 + rbase + i] = acc[i];
    __syncthreads();

    const int rl  = t & 63;
    const int bl0 = t >> 6;
    const size_t obase = (size_t)(bt * 64) * NROWS + (size_t)rt * 64;
#pragma unroll
    for (int p = 0; p < 16; ++p) {
        const int bl = bl0 + p * 4;
        out[obase + (size_t)bl * NROWS + rl] = tile[bl * 65 + rl];
    }
}

extern "C" void kernel_launch(void* const* d_in, const int* in_sizes, int n_in,
                              void* d_out, int out_size, void* d_ws, size_t ws_size,
                              hipStream_t stream) {
    const float* x    = (const float*)d_in[0];
    const float* vals = (const float*)d_in[1];
    // d_in[2] = rows (repeat(arange(NROWS), 32)) -- structure known, unused
    const int*   cols = (const int*)d_in[3];
    float* out = (float*)d_out;

    const size_t xth_bytes = (size_t)NCOLS * BATCH * sizeof(ushort);  // 16 MiB
    if (ws_size >= xth_bytes) {
        uint* xth = (uint*)d_ws;
        dim3 tgrid(NCOLS / 64, BATCH / 64);
        transpose_bf16<<<tgrid, 256, 0, stream>>>(x, xth);
        spmm_v6<<<(NROWS / RB3) * (BATCH / BT3), 256, 0, stream>>>(
            (const ushort*)xth, vals, cols, out);
    } else {
        spmm_fallback<<<(NROWS / 64) * (BATCH / 64), 256, 0, stream>>>(
            x, vals, cols, out);
    }
}

// Round 7
// 49.879 us; speedup vs baseline: 6.3358x; 6.3358x over previous
//
#include <hip/hip_runtime.h>

#define BATCH 1024
#define NCOLS 8192
#define NROWS 8192
#define NNZPR 32
#define BT3   128   // batches per block
#define RB3   32    // rows per block
#define TSTRIDE 130 // output tile row stride (2-way readout: free)

// round-to-nearest-even f32 -> bf16
__device__ __forceinline__ uint f2bf(float f) {
    uint u = __float_as_uint(f);
    return (u + 0x7fffu + ((u >> 16) & 1u)) >> 16;
}

// ---------------------------------------------------------------------------
// Kernel 1: transpose+convert X (BATCH x NCOLS f32) -> XTH (NCOLS x BATCH bf16)
// 32 MB read + 16 MB write, ~8 us. Known good.
// ---------------------------------------------------------------------------
__global__ __launch_bounds__(256) void transpose_bf16(const float* __restrict__ x,
                                                      uint* __restrict__ xth) {
    __shared__ float tile[64][65];
    const int c0 = blockIdx.x * 64;
    const int b0 = blockIdx.y * 64;
    const int t  = threadIdx.x;
    const int tx = t & 63;
    const int ty = t >> 6;

#pragma unroll
    for (int i = 0; i < 16; ++i) {
        const int b = ty + i * 4;
        tile[b][tx] = x[(size_t)(b0 + b) * NCOLS + c0 + tx];
    }
    __syncthreads();

    const int tx2 = t & 31;      // packed-uint column (2 batches)
    const int h   = t >> 5;      // 0..7
#pragma unroll
    for (int i = 0; i < 8; ++i) {
        const int c = h + i * 8;
        const uint lo = f2bf(tile[2 * tx2 + 0][c]);   // 2-way LDS alias: free
        const uint hi = f2bf(tile[2 * tx2 + 1][c]);
        xth[(size_t)(c0 + c) * (BATCH / 2) + (b0 >> 1) + tx2] = lo | (hi << 16);
    }
}

// ---------------------------------------------------------------------------
// Kernel 2 (main): 32-row x 128-batch tiles on bf16 XTH.
//   Memory design proven optimal (r5: FETCH 16.5 MB, WRITE 32 MB).
//   Occupancy controls (r5: VGPR 220; r6: sched_barrier+bounds -> spills):
//     - '#pragma unroll 1' on the pass loop: structural bound on cross-pass
//       load hoisting, no scheduler fence, no register-cap squeeze
//     - disjoint LDS tile + s_pair: each pass writes acc straight to the
//       tile (no runtime-indexed reg array, minimal live state)
//   Depth-2 pipeline WITHIN a pass keeps 8 gathers in flight per wave.
// ---------------------------------------------------------------------------
#define FMAQ(L, V) do {                                      \
    const float v_ = __int_as_float(V);                      \
    ax += __uint_as_float((L).x << 16) * v_;                 \
    ay += __uint_as_float((L).x & 0xffff0000u) * v_;         \
    az += __uint_as_float((L).y << 16) * v_;                 \
    aw += __uint_as_float((L).y & 0xffff0000u) * v_;         \
} while (0)

__global__ __launch_bounds__(256) void spmm_v7(const ushort* __restrict__ xth,
                                               const float* __restrict__ vals,
                                               const int*   __restrict__ cols,
                                               float* __restrict__ out) {
    // tile [32][130] f32 (16640 B) | s_pair 1024 int2 (8192 B) -- disjoint
    __shared__ __align__(16) char smem[RB3 * TSTRIDE * 4 + RB3 * NNZPR * 8];
    float* tile   = (float*)smem;
    int2*  s_pair = (int2*)(smem + RB3 * TSTRIDE * 4);

    const int bid = blockIdx.x;
    const int bt  = bid & 7;         // batch tile -> XCD id (4 MiB L2 slice/XCD)
    const int rt  = bid >> 3;        // row tile 0..255
    const int t   = threadIdx.x;

    const int nnzbase = rt * RB3 * NNZPR;
    for (int i = t; i < RB3 * NNZPR; i += 256) {
        int2 p;
        p.x = cols[nnzbase + i] << 11;          // byte offset: col*BATCH*2
        p.y = __float_as_int(vals[nnzbase + i]);
        s_pair[i] = p;
    }
    __syncthreads();

    const int hw = t >> 5;           // half-wave id 0..7 (row within pass)
    const int sl = t & 31;           // batch-quad within row
    const char* __restrict__ xb = (const char*)xth + (bt * BT3 + sl * 4) * 2;

#pragma unroll 1                     // structural fence: one pass's live set
    for (int pass = 0; pass < 4; ++pass) {
        const int row = pass * 8 + hw;
        const int4* mrow = (const int4*)(s_pair + row * NNZPR);  // 16 int4

        int4 ma = mrow[0], mb = mrow[1];
        uint2 l0 = *(const uint2*)(xb + ma.x);
        uint2 l1 = *(const uint2*)(xb + ma.z);
        uint2 l2 = *(const uint2*)(xb + mb.x);
        uint2 l3 = *(const uint2*)(xb + mb.z);

        float ax = 0.f, ay = 0.f, az = 0.f, aw = 0.f;
#pragma unroll
        for (int g = 0; g < 7; ++g) {
            // prefetch group g+1 (independent of current FMAs)
            int4 na = mrow[2 * g + 2], nb = mrow[2 * g + 3];
            uint2 n0 = *(const uint2*)(xb + na.x);
            uint2 n1 = *(const uint2*)(xb + na.z);
            uint2 n2 = *(const uint2*)(xb + nb.x);
            uint2 n3 = *(const uint2*)(xb + nb.z);
            // consume group g
            FMAQ(l0, ma.y); FMAQ(l1, ma.w);
            FMAQ(l2, mb.y); FMAQ(l3, mb.w);
            ma = na; mb = nb; l0 = n0; l1 = n1; l2 = n2; l3 = n3;
        }
        FMAQ(l0, ma.y); FMAQ(l1, ma.w);
        FMAQ(l2, mb.y); FMAQ(l3, mb.w);

        // write-through to the (disjoint) output tile; no cross-pass state
        float* dst = tile + row * TSTRIDE + sl * 4;   // 8B-aligned
        *(float2*)(dst + 0) = make_float2(ax, ay);
        *(float2*)(dst + 2) = make_float2(az, aw);
    }
    __syncthreads();

    const int rr = t & 31;           // row within tile
    const int bq = t >> 5;           // 0..7
    const size_t obase = (size_t)(bt * BT3) * NROWS + (size_t)(rt * RB3);
#pragma unroll
    for (int p = 0; p < 16; ++p) {
        const int b = p * 8 + bq;    // batch within tile
        // half-wave writes 128 B contiguous, 128B-aligned
        out[obase + (size_t)b * NROWS + rr] = tile[rr * TSTRIDE + b];
    }
}

// ---------------------------------------------------------------------------
// Fallback (ws too small for XTH): scalar gather straight from X.
// ---------------------------------------------------------------------------
__global__ __launch_bounds__(256) void spmm_fallback(const float* __restrict__ x,
                                                     const float* __restrict__ vals,
                                                     const int*   __restrict__ cols,
                                                     float* __restrict__ out) {
    __shared__ __align__(16) char smem[64 * 65 * 4];
    int*   s_col = (int*)smem;
    float* s_val = (float*)(smem + 64 * 32 * 4);

    const int bid  = blockIdx.x;
    const int bt   = bid & 15;
    const int rt   = bid >> 4;
    const int t    = threadIdx.x;
    const int lane = t & 63;
    const int wave = t >> 6;

    const int nnzbase = rt * 64 * NNZPR;
    for (int i = t; i < 64 * NNZPR; i += 256) {
        s_col[i] = cols[nnzbase + i];
        s_val[i] = vals[nnzbase + i];
    }
    __syncthreads();

    const int b = bt * 64 + lane;
    const float* __restrict__ xb = x + (size_t)b * NCOLS;

    const int rbase = wave * 16;
    float acc[16];
#pragma unroll
    for (int i = 0; i < 16; ++i) acc[i] = 0.f;

    for (int i = 0; i < 16; ++i) {
        const int p = (rbase + i) * NNZPR;
        float a = 0.f;
#pragma unroll
        for (int k = 0; k < NNZPR; ++k)
            a += xb[s_col[p + k]] * s_val[p + k];
        acc[i] = a;
    }
    __syncthreads();

    float* tile = (float*)smem;
#pragma unroll
    for (int i = 0; i < 16; ++i)
        tile[lane * 65 + rbase + i] = acc[i];
    __syncthreads();

    const int rl  = t & 63;
    const int bl0 = t >> 6;
    const size_t obase = (size_t)(bt * 64) * NROWS + (size_t)rt * 64;
#pragma unroll
    for (int p = 0; p < 16; ++p) {
        const int bl = bl0 + p * 4;
        out[obase + (size_t)bl * NROWS + rl] = tile[bl * 65 + rl];
    }
}

extern "C" void kernel_launch(void* const* d_in, const int* in_sizes, int n_in,
                              void* d_out, int out_size, void* d_ws, size_t ws_size,
                              hipStream_t stream) {
    const float* x    = (const float*)d_in[0];
    const float* vals = (const float*)d_in[1];
    // d_in[2] = rows (repeat(arange(NROWS), 32)) -- structure known, unused
    const int*   cols = (const int*)d_in[3];
    float* out = (float*)d_out;

    const size_t xth_bytes = (size_t)NCOLS * BATCH * sizeof(ushort);  // 16 MiB
    if (ws_size >= xth_bytes) {
        uint* xth = (uint*)d_ws;
        dim3 tgrid(NCOLS / 64, BATCH / 64);
        transpose_bf16<<<tgrid, 256, 0, stream>>>(x, xth);
        spmm_v7<<<(NROWS / RB3) * (BATCH / BT3), 256, 0, stream>>>(
            (const ushort*)xth, vals, cols, out);
    } else {
        spmm_fallback<<<(NROWS / 64) * (BATCH / 64), 256, 0, stream>>>(
            x, vals, cols, out);
    }
}